// Round 2
// baseline (2238.593 us; speedup 1.0000x reference)
//
#include <hip/hip_runtime.h>
#include <math.h>

// MoE block: B=4,S=2048,D=1024,H=4096,E=8,topk=2.  T=8192 tokens, TK=16384 assignments.
// Sparse grouped-GEMM in bf16 MFMA; router/softmax/aux in fp32.

typedef __attribute__((ext_vector_type(8))) short s16x8;
typedef __attribute__((ext_vector_type(4))) float f32x4;

constexpr int T_ = 8192;
constexpr int D_ = 1024;
constexpr int H_ = 4096;
constexpr int E_ = 8;
constexpr int TK_ = 16384;  // T_ * top_k

// fp32 -> bf16 bits, round-to-nearest-even (finite inputs only)
__device__ __forceinline__ unsigned short f2b(float f) {
  unsigned int u = __builtin_bit_cast(unsigned int, f);
  u += 0x7fffu + ((u >> 16) & 1u);
  return (unsigned short)(u >> 16);
}

// async global->LDS, 16B per lane; LDS dest is wave-uniform base (+ lane*16 by HW)
__device__ __forceinline__ void gload_lds16(const void* g, void* l) {
  __builtin_amdgcn_global_load_lds((const __attribute__((address_space(1))) void*)g,
                                   (__attribute__((address_space(3))) void*)l, 16, 0, 0);
}

// ---------------- pre-pass conversions ----------------

__global__ __launch_bounds__(256) void cvt_x_kernel(const float* __restrict__ x,
                                                    unsigned short* __restrict__ xb) {
  int i = (blockIdx.x * 256 + threadIdx.x) * 4;
  const float4 v = *(const float4*)(x + i);
  ushort4 o;
  o.x = f2b(v.x); o.y = f2b(v.y); o.z = f2b(v.z); o.w = f2b(v.w);
  *(ushort4*)(xb + i) = o;
}

// src [E][R][C] f32  ->  dst [E][C][R] bf16   (grid: (C/32, R/32, E), block (32,8))
__global__ __launch_bounds__(256) void transpose_cvt_kernel(const float* __restrict__ src,
                                                            unsigned short* __restrict__ dst,
                                                            int R, int C) {
  __shared__ float tile[32][33];
  size_t eoff = (size_t)blockIdx.z * R * C;
  int c0 = blockIdx.x * 32, r0 = blockIdx.y * 32;
  int tx = threadIdx.x, ty = threadIdx.y;
#pragma unroll
  for (int j = 0; j < 4; ++j)
    tile[ty + 8 * j][tx] = src[eoff + (size_t)(r0 + ty + 8 * j) * C + c0 + tx];
  __syncthreads();
#pragma unroll
  for (int j = 0; j < 4; ++j)
    dst[eoff + (size_t)(c0 + ty + 8 * j) * R + r0 + tx] = f2b(tile[tx][ty + 8 * j]);
}

// ---------------- router ----------------

__global__ __launch_bounds__(256) void router_kernel(const float* __restrict__ x,
                                                     const float* __restrict__ rw,
                                                     int* __restrict__ top_idx,
                                                     float* __restrict__ top_gate,
                                                     int* __restrict__ counts,
                                                     float* __restrict__ Psum) {
  __shared__ float rws[E_ * D_];  // 32 KB
  const int t = threadIdx.x;
  for (int i = t; i < E_ * D_; i += 256) rws[i] = rw[i];
  __syncthreads();
  const int lane = t & 63, wid = t >> 6;
  const int tok = blockIdx.x * 4 + wid;
  const float* xp = x + (size_t)tok * D_;
  float acc[E_] = {};
  for (int i = lane; i < D_; i += 64) {
    float xv = xp[i];
#pragma unroll
    for (int e = 0; e < E_; ++e) acc[e] += xv * rws[e * D_ + i];
  }
#pragma unroll
  for (int e = 0; e < E_; ++e)
#pragma unroll
    for (int s = 32; s; s >>= 1) acc[e] += __shfl_xor(acc[e], s, 64);
  if (lane == 0) {
    float m = acc[0];
#pragma unroll
    for (int e = 1; e < E_; ++e) m = fmaxf(m, acc[e]);
    float p[E_], sum = 0.f;
#pragma unroll
    for (int e = 0; e < E_; ++e) { p[e] = expf(acc[e] - m); sum += p[e]; }
    float inv = 1.f / sum;
#pragma unroll
    for (int e = 0; e < E_; ++e) { p[e] *= inv; atomicAdd(&Psum[e], p[e]); }
    // top-2, ties -> lowest index (strict >)
    int i0 = 0; float v0 = p[0];
#pragma unroll
    for (int e = 1; e < E_; ++e) if (p[e] > v0) { v0 = p[e]; i0 = e; }
    int i1 = -1; float v1 = -1.f;
#pragma unroll
    for (int e = 0; e < E_; ++e) if (e != i0 && p[e] > v1) { v1 = p[e]; i1 = e; }
    float gs = 1.f / (v0 + v1);
    top_idx[tok * 2] = i0;  top_idx[tok * 2 + 1] = i1;
    top_gate[tok * 2] = v0 * gs;  top_gate[tok * 2 + 1] = v1 * gs;
    atomicAdd(&counts[i0], 1);  atomicAdd(&counts[i1], 1);
  }
}

__global__ void finalize_kernel(const int* __restrict__ counts, const float* __restrict__ Psum,
                                int* __restrict__ offs, float* __restrict__ aux_out) {
  int o = 0; float aux = 0.f;
  for (int e = 0; e < E_; ++e) { offs[e] = o; o += counts[e]; }
  for (int e = 0; e < E_; ++e)
    aux += ((float)counts[e] / (float)TK_) * (Psum[e] / (float)T_);
  aux_out[0] = aux * (float)E_;
}

__global__ __launch_bounds__(256) void assign_kernel(const int* __restrict__ top_idx,
                                                     const float* __restrict__ top_gate,
                                                     const int* __restrict__ offs,
                                                     int* __restrict__ cursor,
                                                     int* __restrict__ slot_token,
                                                     float* __restrict__ slot_gate) {
  int tok = blockIdx.x * 256 + threadIdx.x;
#pragma unroll
  for (int k = 0; k < 2; ++k) {
    int e = top_idx[tok * 2 + k];
    int pos = atomicAdd(&cursor[e], 1);
    int slot = offs[e] + pos;
    slot_token[slot] = tok;
    slot_gate[slot] = top_gate[tok * 2 + k];
  }
}

// ---------------- grouped GEMMs (128x128 tile, 4 waves, BK=32, mfma 16x16x32 bf16) ----------------

__global__ __launch_bounds__(256) void gemm1_kernel(const unsigned short* __restrict__ xb,
                                                    const unsigned short* __restrict__ w1t,
                                                    const float* __restrict__ b1,
                                                    const int* __restrict__ counts,
                                                    const int* __restrict__ offs,
                                                    const int* __restrict__ slot_token,
                                                    unsigned short* __restrict__ hbuf) {
  const int e = blockIdx.x >> 6, mt = blockIdx.x & 63;
  const int cnt = counts[e];
  if (mt * 128 >= cnt) return;
  const int off = offs[e];
  const int n0 = blockIdx.y * 128;
  __shared__ unsigned short As[128 * 32];
  __shared__ unsigned short Bs[128 * 32];
  const int t = threadIdx.x, lane = t & 63, wid = t >> 6;
  const int wm = (wid >> 1) * 64, wn = (wid & 1) * 64;
  const int fr = lane & 15, fk = (lane >> 4) * 8;

  const unsigned short* a_src[2]; const unsigned short* b_src[2];
  unsigned short* a_dst[2]; unsigned short* b_dst[2];
#pragma unroll
  for (int j = 0; j < 2; ++j) {
    int c = t + 256 * j;
    int row = c >> 2, k8 = (c & 3) * 8;
    int slot = off + mt * 128 + row;
    slot = slot < TK_ ? slot : TK_ - 1;  // clamp: safe addr, masked at store
    a_src[j] = xb + (size_t)slot_token[slot] * D_ + k8;
    b_src[j] = w1t + ((size_t)e * H_ + n0 + row) * D_ + k8;
    int cb = wid * 64 + 256 * j;  // wave-uniform chunk base
    a_dst[j] = As + cb * 8;
    b_dst[j] = Bs + cb * 8;
  }
  f32x4 acc[4][4] = {};
  for (int k0 = 0; k0 < D_; k0 += 32) {
    gload_lds16(a_src[0] + k0, a_dst[0]);
    gload_lds16(a_src[1] + k0, a_dst[1]);
    gload_lds16(b_src[0] + k0, b_dst[0]);
    gload_lds16(b_src[1] + k0, b_dst[1]);
    __syncthreads();
    s16x8 af[4], bfr[4];
#pragma unroll
    for (int m = 0; m < 4; ++m)
      af[m] = *(const s16x8*)(As + (wm + m * 16 + fr) * 32 + fk);
#pragma unroll
    for (int n = 0; n < 4; ++n)
      bfr[n] = *(const s16x8*)(Bs + (wn + n * 16 + fr) * 32 + fk);
#pragma unroll
    for (int m = 0; m < 4; ++m)
#pragma unroll
      for (int n = 0; n < 4; ++n)
        acc[m][n] = __builtin_amdgcn_mfma_f32_16x16x32_bf16(af[m], bfr[n], acc[m][n], 0, 0, 0);
    __syncthreads();
  }
  const float* b1e = b1 + (size_t)e * H_;
  const int rbase = (lane >> 4) * 4;
#pragma unroll
  for (int m = 0; m < 4; ++m) {
#pragma unroll
    for (int r = 0; r < 4; ++r) {
      int rit = wm + m * 16 + rbase + r;
      if (mt * 128 + rit < cnt) {
        size_t hrow = (size_t)(off + mt * 128 + rit) * H_;
#pragma unroll
        for (int n = 0; n < 4; ++n) {
          int gc = n0 + wn + n * 16 + fr;
          float v = acc[m][n][r] + b1e[gc];
          float g = 0.5f * v * (1.0f + erff(v * 0.70710678118654752f));  // exact gelu
          hbuf[hrow + gc] = f2b(g);
        }
      }
    }
  }
}

__global__ __launch_bounds__(256) void gemm2_kernel(const unsigned short* __restrict__ hbuf,
                                                    const unsigned short* __restrict__ w2t,
                                                    const float* __restrict__ b2,
                                                    const int* __restrict__ counts,
                                                    const int* __restrict__ offs,
                                                    const int* __restrict__ slot_token,
                                                    const float* __restrict__ slot_gate,
                                                    float* __restrict__ out) {
  const int e = blockIdx.x >> 6, mt = blockIdx.x & 63;
  const int cnt = counts[e];
  if (mt * 128 >= cnt) return;
  const int off = offs[e];
  const int n0 = blockIdx.y * 128;
  __shared__ unsigned short As[128 * 32];
  __shared__ unsigned short Bs[128 * 32];
  const int t = threadIdx.x, lane = t & 63, wid = t >> 6;
  const int wm = (wid >> 1) * 64, wn = (wid & 1) * 64;
  const int fr = lane & 15, fk = (lane >> 4) * 8;

  const unsigned short* a_src[2]; const unsigned short* b_src[2];
  unsigned short* a_dst[2]; unsigned short* b_dst[2];
#pragma unroll
  for (int j = 0; j < 2; ++j) {
    int c = t + 256 * j;
    int row = c >> 2, k8 = (c & 3) * 8;
    int slot = off + mt * 128 + row;
    slot = slot < TK_ ? slot : TK_ - 1;
    a_src[j] = hbuf + (size_t)slot * H_ + k8;  // h rows are contiguous slots
    b_src[j] = w2t + ((size_t)e * D_ + n0 + row) * H_ + k8;
    int cb = wid * 64 + 256 * j;
    a_dst[j] = As + cb * 8;
    b_dst[j] = Bs + cb * 8;
  }
  f32x4 acc[4][4] = {};
  for (int k0 = 0; k0 < H_; k0 += 32) {
    gload_lds16(a_src[0] + k0, a_dst[0]);
    gload_lds16(a_src[1] + k0, a_dst[1]);
    gload_lds16(b_src[0] + k0, b_dst[0]);
    gload_lds16(b_src[1] + k0, b_dst[1]);
    __syncthreads();
    s16x8 af[4], bfr[4];
#pragma unroll
    for (int m = 0; m < 4; ++m)
      af[m] = *(const s16x8*)(As + (wm + m * 16 + fr) * 32 + fk);
#pragma unroll
    for (int n = 0; n < 4; ++n)
      bfr[n] = *(const s16x8*)(Bs + (wn + n * 16 + fr) * 32 + fk);
#pragma unroll
    for (int m = 0; m < 4; ++m)
#pragma unroll
      for (int n = 0; n < 4; ++n)
        acc[m][n] = __builtin_amdgcn_mfma_f32_16x16x32_bf16(af[m], bfr[n], acc[m][n], 0, 0, 0);
    __syncthreads();
  }
  const float* b2e = b2 + (size_t)e * D_;
  const int rbase = (lane >> 4) * 4;
#pragma unroll
  for (int m = 0; m < 4; ++m) {
#pragma unroll
    for (int r = 0; r < 4; ++r) {
      int rit = wm + m * 16 + rbase + r;
      if (mt * 128 + rit < cnt) {
        int slot = off + mt * 128 + rit;
        int tok = slot_token[slot];
        float g = slot_gate[slot];
#pragma unroll
        for (int n = 0; n < 4; ++n) {
          int gc = n0 + wn + n * 16 + fr;
          float v = acc[m][n][r] + b2e[gc];
          atomicAdd(&out[(size_t)tok * D_ + gc], g * v);  // exactly 2 adds/elem, commutative
        }
      }
    }
  }
}

// ---------------- launch ----------------

extern "C" void kernel_launch(void* const* d_in, const int* in_sizes, int n_in,
                              void* d_out, int out_size, void* d_ws, size_t ws_size,
                              hipStream_t stream) {
  const float* x  = (const float*)d_in[0];
  const float* rw = (const float*)d_in[1];
  const float* w1 = (const float*)d_in[2];
  const float* b1 = (const float*)d_in[3];
  const float* w2 = (const float*)d_in[4];
  const float* b2 = (const float*)d_in[5];
  float* out = (float*)d_out;

  char* ws = (char*)d_ws;
  // small region (zeroed): counts, cursor, Psum, offs
  int*   counts = (int*)(ws + 0);
  int*   cursor = (int*)(ws + 32);
  float* Psum   = (float*)(ws + 64);
  int*   offs   = (int*)(ws + 96);
  int*   top_idx    = (int*)(ws + 256);
  float* top_gate   = (float*)(ws + 256 + 65536);
  int*   slot_token = (int*)(ws + 256 + 2 * 65536);
  float* slot_gate  = (float*)(ws + 256 + 3 * 65536);
  const size_t MB = 1u << 20;
  unsigned short* xb   = (unsigned short*)(ws + 1 * MB);    // 16 MB
  unsigned short* w1t  = (unsigned short*)(ws + 18 * MB);   // 64 MB  [E][H][D] bf16
  unsigned short* w2t  = (unsigned short*)(ws + 82 * MB);   // 64 MB  [E][D][H] bf16
  unsigned short* hbuf = (unsigned short*)(ws + 146 * MB);  // 128 MB [TK][H] bf16
  // total ws use ~274 MB

  hipMemsetAsync(d_out, 0, (size_t)out_size * sizeof(float), stream);
  hipMemsetAsync(d_ws, 0, 256, stream);

  cvt_x_kernel<<<T_ * D_ / 1024, 256, 0, stream>>>(x, xb);
  transpose_cvt_kernel<<<dim3(H_ / 32, D_ / 32, E_), dim3(32, 8), 0, stream>>>(w1, w1t, D_, H_);
  transpose_cvt_kernel<<<dim3(D_ / 32, H_ / 32, E_), dim3(32, 8), 0, stream>>>(w2, w2t, H_, D_);
  router_kernel<<<T_ / 4, 256, 0, stream>>>(x, rw, top_idx, top_gate, counts, Psum);
  finalize_kernel<<<1, 1, 0, stream>>>(counts, Psum, offs, out + (size_t)T_ * D_);
  assign_kernel<<<T_ / 256, 256, 0, stream>>>(top_idx, top_gate, offs, cursor,
                                              slot_token, slot_gate);
  gemm1_kernel<<<dim3(512, H_ / 128), 256, 0, stream>>>(xb, w1t, b1, counts, offs,
                                                        slot_token, hbuf);
  gemm2_kernel<<<dim3(512, D_ / 128), 256, 0, stream>>>(hbuf, w2t, b2, counts, offs,
                                                        slot_token, slot_gate, out);
}

// Round 3
// 1435.063 us; speedup vs baseline: 1.5599x; 1.5599x over previous
//
#include <hip/hip_runtime.h>
#include <math.h>

// MoE block: B=4,S=2048,D=1024,H=4096,E=8,topk=2.  T=8192 tokens, TK=16384 assignments.
// Sparse grouped-GEMM in bf16 MFMA; router/softmax/aux in fp32.

typedef __attribute__((ext_vector_type(8))) short s16x8;
typedef __attribute__((ext_vector_type(4))) float f32x4;

constexpr int T_ = 8192;
constexpr int D_ = 1024;
constexpr int H_ = 4096;
constexpr int E_ = 8;
constexpr int TK_ = 16384;  // T_ * top_k

// fp32 -> bf16 bits, round-to-nearest-even (finite inputs only)
__device__ __forceinline__ unsigned short f2b(float f) {
  unsigned int u = __builtin_bit_cast(unsigned int, f);
  u += 0x7fffu + ((u >> 16) & 1u);
  return (unsigned short)(u >> 16);
}

// async global->LDS, 16B per lane; LDS dest is wave-uniform base (+ lane*16 by HW)
__device__ __forceinline__ void gload_lds16(const void* g, void* l) {
  __builtin_amdgcn_global_load_lds((const __attribute__((address_space(1))) void*)g,
                                   (__attribute__((address_space(3))) void*)l, 16, 0, 0);
}

// ---------------- pre-pass conversions ----------------

__global__ __launch_bounds__(256) void cvt_x_kernel(const float* __restrict__ x,
                                                    unsigned short* __restrict__ xb) {
  int i = (blockIdx.x * 256 + threadIdx.x) * 4;
  const float4 v = *(const float4*)(x + i);
  ushort4 o;
  o.x = f2b(v.x); o.y = f2b(v.y); o.z = f2b(v.z); o.w = f2b(v.w);
  *(ushort4*)(xb + i) = o;
}

// src [E][R][C] f32  ->  dst [E][C][R] bf16   (grid: (C/32, R/32, E), block (32,8))
__global__ __launch_bounds__(256) void transpose_cvt_kernel(const float* __restrict__ src,
                                                            unsigned short* __restrict__ dst,
                                                            int R, int C) {
  __shared__ float tile[32][33];
  size_t eoff = (size_t)blockIdx.z * R * C;
  int c0 = blockIdx.x * 32, r0 = blockIdx.y * 32;
  int tx = threadIdx.x, ty = threadIdx.y;
#pragma unroll
  for (int j = 0; j < 4; ++j)
    tile[ty + 8 * j][tx] = src[eoff + (size_t)(r0 + ty + 8 * j) * C + c0 + tx];
  __syncthreads();
#pragma unroll
  for (int j = 0; j < 4; ++j)
    dst[eoff + (size_t)(c0 + ty + 8 * j) * R + r0 + tx] = f2b(tile[tx][ty + 8 * j]);
}

// ---------------- router ----------------
// 128 blocks x 64 tokens; per-block LDS aggregation of Psum/counts (Guideline 12:
// 82K hot global atomics -> 1K). Wave-per-token, float4 loads.

__global__ __launch_bounds__(256) void router_kernel(const float* __restrict__ x,
                                                     const float* __restrict__ rw,
                                                     int* __restrict__ top_idx,
                                                     float* __restrict__ top_gate,
                                                     int* __restrict__ counts,
                                                     float* __restrict__ Psum) {
  __shared__ float rws[E_ * D_];  // 32 KB
  __shared__ float lPsum[E_];
  __shared__ int lCnt[E_];
  const int t = threadIdx.x;
  if (t < E_) { lPsum[t] = 0.f; lCnt[t] = 0; }
  for (int i = t; i < E_ * D_ / 4; i += 256)
    ((float4*)rws)[i] = ((const float4*)rw)[i];
  __syncthreads();
  const int lane = t & 63, wid = t >> 6;
  for (int it = 0; it < 16; ++it) {
    const int tok = blockIdx.x * 64 + wid * 16 + it;
    const float* xp = x + (size_t)tok * D_;
    float acc[E_] = {};
    for (int i0 = 0; i0 < D_; i0 += 256) {
      const float4 xv = *(const float4*)(xp + i0 + lane * 4);
#pragma unroll
      for (int e = 0; e < E_; ++e) {
        const float4 wv = *(const float4*)(rws + e * D_ + i0 + lane * 4);
        acc[e] += xv.x * wv.x + xv.y * wv.y + xv.z * wv.z + xv.w * wv.w;
      }
    }
#pragma unroll
    for (int e = 0; e < E_; ++e)
#pragma unroll
      for (int s = 32; s; s >>= 1) acc[e] += __shfl_xor(acc[e], s, 64);
    if (lane == 0) {
      float m = acc[0];
#pragma unroll
      for (int e = 1; e < E_; ++e) m = fmaxf(m, acc[e]);
      float p[E_], sum = 0.f;
#pragma unroll
      for (int e = 0; e < E_; ++e) { p[e] = expf(acc[e] - m); sum += p[e]; }
      float inv = 1.f / sum;
#pragma unroll
      for (int e = 0; e < E_; ++e) { p[e] *= inv; atomicAdd(&lPsum[e], p[e]); }
      // top-2, ties -> lowest index (strict >)
      int i0 = 0; float v0 = p[0];
#pragma unroll
      for (int e = 1; e < E_; ++e) if (p[e] > v0) { v0 = p[e]; i0 = e; }
      int i1 = -1; float v1 = -1.f;
#pragma unroll
      for (int e = 0; e < E_; ++e) if (e != i0 && p[e] > v1) { v1 = p[e]; i1 = e; }
      float gs = 1.f / (v0 + v1);
      top_idx[tok * 2] = i0;  top_idx[tok * 2 + 1] = i1;
      top_gate[tok * 2] = v0 * gs;  top_gate[tok * 2 + 1] = v1 * gs;
      atomicAdd(&lCnt[i0], 1);  atomicAdd(&lCnt[i1], 1);
    }
  }
  __syncthreads();
  if (t < E_) {
    atomicAdd(&Psum[t], lPsum[t]);
    atomicAdd(&counts[t], lCnt[t]);
  }
}

__global__ void finalize_kernel(const int* __restrict__ counts, const float* __restrict__ Psum,
                                int* __restrict__ offs, float* __restrict__ aux_out) {
  int o = 0; float aux = 0.f;
  for (int e = 0; e < E_; ++e) { offs[e] = o; o += counts[e]; }
  for (int e = 0; e < E_; ++e)
    aux += ((float)counts[e] / (float)TK_) * (Psum[e] / (float)T_);
  aux_out[0] = aux * (float)E_;
}

__global__ __launch_bounds__(256) void assign_kernel(const int* __restrict__ top_idx,
                                                     const float* __restrict__ top_gate,
                                                     const int* __restrict__ offs,
                                                     int* __restrict__ cursor,
                                                     int* __restrict__ slot_token,
                                                     float* __restrict__ slot_gate) {
  int tok = blockIdx.x * 256 + threadIdx.x;
#pragma unroll
  for (int k = 0; k < 2; ++k) {
    int e = top_idx[tok * 2 + k];
    int pos = atomicAdd(&cursor[e], 1);
    int slot = offs[e] + pos;
    slot_token[slot] = tok;
    slot_gate[slot] = top_gate[tok * 2 + k];
  }
}

// ---------------- grouped GEMMs (128x128 tile, 4 waves, BK=32, mfma 16x16x32 bf16) ----------------

__global__ __launch_bounds__(256) void gemm1_kernel(const unsigned short* __restrict__ xb,
                                                    const unsigned short* __restrict__ w1t,
                                                    const float* __restrict__ b1,
                                                    const int* __restrict__ counts,
                                                    const int* __restrict__ offs,
                                                    const int* __restrict__ slot_token,
                                                    unsigned short* __restrict__ hbuf) {
  const int e = blockIdx.x >> 6, mt = blockIdx.x & 63;
  const int cnt = counts[e];
  if (mt * 128 >= cnt) return;
  const int off = offs[e];
  const int n0 = blockIdx.y * 128;
  __shared__ unsigned short As[128 * 32];
  __shared__ unsigned short Bs[128 * 32];
  const int t = threadIdx.x, lane = t & 63, wid = t >> 6;
  const int wm = (wid >> 1) * 64, wn = (wid & 1) * 64;
  const int fr = lane & 15, fk = (lane >> 4) * 8;

  const unsigned short* a_src[2]; const unsigned short* b_src[2];
  unsigned short* a_dst[2]; unsigned short* b_dst[2];
#pragma unroll
  for (int j = 0; j < 2; ++j) {
    int c = t + 256 * j;
    int row = c >> 2, k8 = (c & 3) * 8;
    int slot = off + mt * 128 + row;
    slot = slot < TK_ ? slot : TK_ - 1;  // clamp: safe addr, masked at store
    a_src[j] = xb + (size_t)slot_token[slot] * D_ + k8;
    b_src[j] = w1t + ((size_t)e * H_ + n0 + row) * D_ + k8;
    int cb = wid * 64 + 256 * j;  // wave-uniform chunk base
    a_dst[j] = As + cb * 8;
    b_dst[j] = Bs + cb * 8;
  }
  f32x4 acc[4][4] = {};
  for (int k0 = 0; k0 < D_; k0 += 32) {
    gload_lds16(a_src[0] + k0, a_dst[0]);
    gload_lds16(a_src[1] + k0, a_dst[1]);
    gload_lds16(b_src[0] + k0, b_dst[0]);
    gload_lds16(b_src[1] + k0, b_dst[1]);
    __syncthreads();
    s16x8 af[4], bfr[4];
#pragma unroll
    for (int m = 0; m < 4; ++m)
      af[m] = *(const s16x8*)(As + (wm + m * 16 + fr) * 32 + fk);
#pragma unroll
    for (int n = 0; n < 4; ++n)
      bfr[n] = *(const s16x8*)(Bs + (wn + n * 16 + fr) * 32 + fk);
#pragma unroll
    for (int m = 0; m < 4; ++m)
#pragma unroll
      for (int n = 0; n < 4; ++n)
        acc[m][n] = __builtin_amdgcn_mfma_f32_16x16x32_bf16(af[m], bfr[n], acc[m][n], 0, 0, 0);
    __syncthreads();
  }
  const float* b1e = b1 + (size_t)e * H_;
  const int rbase = (lane >> 4) * 4;
#pragma unroll
  for (int m = 0; m < 4; ++m) {
#pragma unroll
    for (int r = 0; r < 4; ++r) {
      int rit = wm + m * 16 + rbase + r;
      if (mt * 128 + rit < cnt) {
        size_t hrow = (size_t)(off + mt * 128 + rit) * H_;
#pragma unroll
        for (int n = 0; n < 4; ++n) {
          int gc = n0 + wn + n * 16 + fr;
          float v = acc[m][n][r] + b1e[gc];
          float g = 0.5f * v * (1.0f + erff(v * 0.70710678118654752f));  // exact gelu
          hbuf[hrow + gc] = f2b(g);
        }
      }
    }
  }
}

__global__ __launch_bounds__(256) void gemm2_kernel(const unsigned short* __restrict__ hbuf,
                                                    const unsigned short* __restrict__ w2t,
                                                    const float* __restrict__ b2,
                                                    const int* __restrict__ counts,
                                                    const int* __restrict__ offs,
                                                    const int* __restrict__ slot_token,
                                                    const float* __restrict__ slot_gate,
                                                    float* __restrict__ out) {
  const int e = blockIdx.x >> 6, mt = blockIdx.x & 63;
  const int cnt = counts[e];
  if (mt * 128 >= cnt) return;
  const int off = offs[e];
  const int n0 = blockIdx.y * 128;
  __shared__ unsigned short As[128 * 32];
  __shared__ unsigned short Bs[128 * 32];
  const int t = threadIdx.x, lane = t & 63, wid = t >> 6;
  const int wm = (wid >> 1) * 64, wn = (wid & 1) * 64;
  const int fr = lane & 15, fk = (lane >> 4) * 8;

  const unsigned short* a_src[2]; const unsigned short* b_src[2];
  unsigned short* a_dst[2]; unsigned short* b_dst[2];
#pragma unroll
  for (int j = 0; j < 2; ++j) {
    int c = t + 256 * j;
    int row = c >> 2, k8 = (c & 3) * 8;
    int slot = off + mt * 128 + row;
    slot = slot < TK_ ? slot : TK_ - 1;
    a_src[j] = hbuf + (size_t)slot * H_ + k8;  // h rows are contiguous slots
    b_src[j] = w2t + ((size_t)e * D_ + n0 + row) * H_ + k8;
    int cb = wid * 64 + 256 * j;
    a_dst[j] = As + cb * 8;
    b_dst[j] = Bs + cb * 8;
  }
  f32x4 acc[4][4] = {};
  for (int k0 = 0; k0 < H_; k0 += 32) {
    gload_lds16(a_src[0] + k0, a_dst[0]);
    gload_lds16(a_src[1] + k0, a_dst[1]);
    gload_lds16(b_src[0] + k0, b_dst[0]);
    gload_lds16(b_src[1] + k0, b_dst[1]);
    __syncthreads();
    s16x8 af[4], bfr[4];
#pragma unroll
    for (int m = 0; m < 4; ++m)
      af[m] = *(const s16x8*)(As + (wm + m * 16 + fr) * 32 + fk);
#pragma unroll
    for (int n = 0; n < 4; ++n)
      bfr[n] = *(const s16x8*)(Bs + (wn + n * 16 + fr) * 32 + fk);
#pragma unroll
    for (int m = 0; m < 4; ++m)
#pragma unroll
      for (int n = 0; n < 4; ++n)
        acc[m][n] = __builtin_amdgcn_mfma_f32_16x16x32_bf16(af[m], bfr[n], acc[m][n], 0, 0, 0);
    __syncthreads();
  }
  const float* b2e = b2 + (size_t)e * D_;
  const int rbase = (lane >> 4) * 4;
#pragma unroll
  for (int m = 0; m < 4; ++m) {
#pragma unroll
    for (int r = 0; r < 4; ++r) {
      int rit = wm + m * 16 + rbase + r;
      if (mt * 128 + rit < cnt) {
        int slot = off + mt * 128 + rit;
        int tok = slot_token[slot];
        float g = slot_gate[slot];
#pragma unroll
        for (int n = 0; n < 4; ++n) {
          int gc = n0 + wn + n * 16 + fr;
          float v = acc[m][n][r] + b2e[gc];
          atomicAdd(&out[(size_t)tok * D_ + gc], g * v);  // exactly 2 adds/elem, commutative
        }
      }
    }
  }
}

// ---------------- launch ----------------

extern "C" void kernel_launch(void* const* d_in, const int* in_sizes, int n_in,
                              void* d_out, int out_size, void* d_ws, size_t ws_size,
                              hipStream_t stream) {
  const float* x  = (const float*)d_in[0];
  const float* rw = (const float*)d_in[1];
  const float* w1 = (const float*)d_in[2];
  const float* b1 = (const float*)d_in[3];
  const float* w2 = (const float*)d_in[4];
  const float* b2 = (const float*)d_in[5];
  float* out = (float*)d_out;

  char* ws = (char*)d_ws;
  // small region (zeroed): counts, cursor, Psum, offs
  int*   counts = (int*)(ws + 0);
  int*   cursor = (int*)(ws + 32);
  float* Psum   = (float*)(ws + 64);
  int*   offs   = (int*)(ws + 96);
  int*   top_idx    = (int*)(ws + 256);
  float* top_gate   = (float*)(ws + 256 + 65536);
  int*   slot_token = (int*)(ws + 256 + 2 * 65536);
  float* slot_gate  = (float*)(ws + 256 + 3 * 65536);
  const size_t MB = 1u << 20;
  unsigned short* xb   = (unsigned short*)(ws + 1 * MB);    // 16 MB
  unsigned short* w1t  = (unsigned short*)(ws + 18 * MB);   // 64 MB  [E][H][D] bf16
  unsigned short* w2t  = (unsigned short*)(ws + 82 * MB);   // 64 MB  [E][D][H] bf16
  unsigned short* hbuf = (unsigned short*)(ws + 146 * MB);  // 128 MB [TK][H] bf16
  // total ws use ~274 MB

  hipMemsetAsync(d_out, 0, (size_t)out_size * sizeof(float), stream);
  hipMemsetAsync(d_ws, 0, 256, stream);

  cvt_x_kernel<<<T_ * D_ / 1024, 256, 0, stream>>>(x, xb);
  transpose_cvt_kernel<<<dim3(H_ / 32, D_ / 32, E_), dim3(32, 8), 0, stream>>>(w1, w1t, D_, H_);
  transpose_cvt_kernel<<<dim3(D_ / 32, H_ / 32, E_), dim3(32, 8), 0, stream>>>(w2, w2t, H_, D_);
  router_kernel<<<T_ / 64, 256, 0, stream>>>(x, rw, top_idx, top_gate, counts, Psum);
  finalize_kernel<<<1, 1, 0, stream>>>(counts, Psum, offs, out + (size_t)T_ * D_);
  assign_kernel<<<T_ / 256, 256, 0, stream>>>(top_idx, top_gate, offs, cursor,
                                              slot_token, slot_gate);
  gemm1_kernel<<<dim3(512, H_ / 128), 256, 0, stream>>>(xb, w1t, b1, counts, offs,
                                                        slot_token, hbuf);
  gemm2_kernel<<<dim3(512, D_ / 128), 256, 0, stream>>>(hbuf, w2t, b2, counts, offs,
                                                        slot_token, slot_gate, out);
}